// Round 2
// baseline (4661.563 us; speedup 1.0000x reference)
//
#include <hip/hip_runtime.h>
#include <cstddef>

#define NN   262144
#define NE   2097152
#define DIN  96
#define HH   64
#define EDD  5
#define AOUT 20
#define CHUNK 32768

__device__ __forceinline__ float sigmoidf_(float x) { return 1.0f / (1.0f + __expf(-x)); }

// ---------------- generic tiled GEMM: C = act(A[M,K] @ W[K,ncols] + bias) ----------------
#define TM 64
#define TN 64
#define KC 32

__global__ __launch_bounds__(256)
void gemm_bias_act(const float* __restrict__ A, int lda,
                   const float* __restrict__ W, int ldw,
                   const float* __restrict__ bias,
                   float* __restrict__ C, int ldc,
                   int K, int ncols, int act)
{
    __shared__ float sA[TM][KC + 1];
    __shared__ float sW[KC][TN];
    const int t = threadIdx.x;
    const int tx = t & 15, ty = t >> 4;
    const int row0 = blockIdx.x * TM;
    const int c0 = blockIdx.y * TN;
    float acc[4][4] = {{0.f}};
    for (int k0 = 0; k0 < K; k0 += KC) {
        // stage A tile (64 x 32)
        for (int i = t; i < TM * KC / 4; i += 256) {
            int r = i >> 3, cq = i & 7;
            float4 v = *(const float4*)(A + (size_t)(row0 + r) * lda + (k0 + cq * 4));
            sA[r][cq * 4 + 0] = v.x; sA[r][cq * 4 + 1] = v.y;
            sA[r][cq * 4 + 2] = v.z; sA[r][cq * 4 + 3] = v.w;
        }
        // stage W tile (32 x 64)
        for (int i = t; i < KC * TN / 4; i += 256) {
            int r = i >> 4, cq = i & 15;
            int c = c0 + cq * 4;
            float4 v = make_float4(0.f, 0.f, 0.f, 0.f);
            if (c < ncols) v = *(const float4*)(W + (size_t)(k0 + r) * ldw + c);
            *(float4*)&sW[r][cq * 4] = v;
        }
        __syncthreads();
#pragma unroll
        for (int k = 0; k < KC; ++k) {
            float a0 = sA[ty * 4 + 0][k], a1 = sA[ty * 4 + 1][k];
            float a2 = sA[ty * 4 + 2][k], a3 = sA[ty * 4 + 3][k];
            float4 w = *(const float4*)&sW[k][tx * 4];
            acc[0][0] += a0 * w.x; acc[0][1] += a0 * w.y; acc[0][2] += a0 * w.z; acc[0][3] += a0 * w.w;
            acc[1][0] += a1 * w.x; acc[1][1] += a1 * w.y; acc[1][2] += a1 * w.z; acc[1][3] += a1 * w.w;
            acc[2][0] += a2 * w.x; acc[2][1] += a2 * w.y; acc[2][2] += a2 * w.z; acc[2][3] += a2 * w.w;
            acc[3][0] += a3 * w.x; acc[3][1] += a3 * w.y; acc[3][2] += a3 * w.z; acc[3][3] += a3 * w.w;
        }
        __syncthreads();
    }
#pragma unroll
    for (int i = 0; i < 4; ++i) {
        size_t rr = (size_t)(row0 + ty * 4 + i);
#pragma unroll
        for (int j = 0; j < 4; ++j) {
            int cc = c0 + tx * 4 + j;
            if (cc < ncols) {
                float v = acc[i][j] + bias[cc];
                if (act) v = fmaxf(v, 0.f);
                C[rr * ldc + cc] = v;
            }
        }
    }
}

// ---------------- degree + self-loop attr sums ----------------
__global__ __launch_bounds__(256)
void deg_kernel(const int* __restrict__ ei, const float* __restrict__ ea,
                float* __restrict__ deg, float* __restrict__ loopa)
{
    int e = blockIdx.x * 256 + threadIdx.x;
    int d = ei[NE + e];
    atomicAdd(deg + d, 1.f);
    const float* p = ea + (size_t)e * EDD;
#pragma unroll
    for (int j = 0; j < EDD; ++j) atomicAdd(loopa + (size_t)d * EDD + j, p[j]);
}

__global__ __launch_bounds__(256)
void loopdiv_kernel(const float* __restrict__ deg, float* __restrict__ loopa)
{
    int n = blockIdx.x * 256 + threadIdx.x;
    float inv = 1.f / fmaxf(deg[n], 1.f);
#pragma unroll
    for (int j = 0; j < EDD; ++j) loopa[(size_t)n * EDD + j] *= inv;
}

// ---------------- edge pass 1: logits + segment max ----------------
__global__ __launch_bounds__(256)
void edge_logits_kernel(const int* __restrict__ ei, const float* __restrict__ ea,
                        const float* __restrict__ loopa,
                        const float* __restrict__ xl, const float* __restrict__ xr,
                        const float* __restrict__ We, const float* __restrict__ att,
                        float* __restrict__ logits, unsigned* __restrict__ mkey)
{
    __shared__ float sWe[EDD][HH];
    __shared__ float sAtt[HH];
    const int t = threadIdx.x;
    for (int i = t; i < EDD * HH; i += 256) sWe[i / HH][i % HH] = We[i];  // 320 > 256: must loop
    if (t < HH) sAtt[t] = att[t];
    __syncthreads();
    const int lg = t & 15;
    int group = (blockIdx.x * 256 + t) >> 4;
    const int ngroups = (gridDim.x * 256) >> 4;
    const int total = NE + NN;
    for (int e = group; e < total; e += ngroups) {
        int s, d; float a0, a1, a2, a3, a4;
        if (e < NE) {
            s = ei[e]; d = ei[NE + e];
            const float* p = ea + (size_t)e * EDD;
            a0 = p[0]; a1 = p[1]; a2 = p[2]; a3 = p[3]; a4 = p[4];
        } else {
            s = d = e - NE;
            const float* p = loopa + (size_t)s * EDD;
            a0 = p[0]; a1 = p[1]; a2 = p[2]; a3 = p[3]; a4 = p[4];
        }
        const int c = lg * 4;
        float4 vl = *(const float4*)(xl + (size_t)s * HH + c);
        float4 vr = *(const float4*)(xr + (size_t)d * HH + c);
        const float* pl = (const float*)&vl;
        const float* pr = (const float*)&vr;
        float part = 0.f;
#pragma unroll
        for (int i = 0; i < 4; ++i) {
            float w = a0 * sWe[0][c + i] + a1 * sWe[1][c + i] + a2 * sWe[2][c + i]
                    + a3 * sWe[3][c + i] + a4 * sWe[4][c + i];
            float v = pl[i] + pr[i] + w;
            v = v > 0.f ? v : 0.2f * v;
            part += v * sAtt[c + i];
        }
        part += __shfl_xor(part, 1);
        part += __shfl_xor(part, 2);
        part += __shfl_xor(part, 4);
        part += __shfl_xor(part, 8);
        if (lg == 0) {
            logits[e] = part;
            unsigned u = __float_as_uint(part);
            unsigned key = (u & 0x80000000u) ? ~u : (u | 0x80000000u);
            atomicMax(mkey + d, key);
        }
    }
}

__global__ __launch_bounds__(256)
void decode_kernel(const unsigned* __restrict__ mkey, float* __restrict__ mm)
{
    int n = blockIdx.x * 256 + threadIdx.x;
    unsigned key = mkey[n];
    unsigned u = (key & 0x80000000u) ? (key ^ 0x80000000u) : ~key;
    mm[n] = __uint_as_float(u);
}

// ---------------- edge pass 2: p, denom, weighted aggregate ----------------
__global__ __launch_bounds__(256)
void edge_acc_kernel(const int* __restrict__ ei,
                     const float* __restrict__ xl, const float* __restrict__ logits,
                     const float* __restrict__ mm, float* __restrict__ den,
                     float* __restrict__ agg)
{
    const int t = threadIdx.x;
    const int lg = t & 15;
    int group = (blockIdx.x * 256 + t) >> 4;
    const int ngroups = (gridDim.x * 256) >> 4;
    const int total = NE + NN;
    for (int e = group; e < total; e += ngroups) {
        int s, d;
        if (e < NE) { s = ei[e]; d = ei[NE + e]; }
        else { s = d = e - NE; }
        float p = __expf(logits[e] - mm[d]);
        const int c = lg * 4;
        float4 v = *(const float4*)(xl + (size_t)s * HH + c);
        float* ag = agg + (size_t)d * HH + c;
        atomicAdd(ag + 0, p * v.x);
        atomicAdd(ag + 1, p * v.y);
        atomicAdd(ag + 2, p * v.z);
        atomicAdd(ag + 3, p * v.w);
        if (lg == 0) atomicAdd(den + d, p);
    }
}

// ---------------- h_gat = relu(agg/den + bias) -> hcat left half ----------------
__global__ __launch_bounds__(256)
void hgat_kernel(const float* __restrict__ agg, const float* __restrict__ den,
                 const float* __restrict__ gbias, float* __restrict__ hcat)
{
    int idx = blockIdx.x * 256 + threadIdx.x;
    int n = idx >> 6, c = idx & 63;
    float v = agg[idx] / den[n] + gbias[c];
    hcat[(size_t)n * 128 + c] = fmaxf(v, 0.f);
}

// ---------------- GRU elementwise ----------------
__global__ __launch_bounds__(256)
void gru_kernel(const float* __restrict__ G, const float* __restrict__ hidden,
                float* __restrict__ outh, int row0)
{
    int idx = blockIdx.x * 256 + threadIdx.x;
    int r_ = idx >> 7, j = idx & 127;
    size_t gb = (size_t)r_ * 384;
    const float* G2 = G + (size_t)CHUNK * 384;
    float gir = G[gb + j], giz = G[gb + 128 + j], gin = G[gb + 256 + j];
    float ghr = G2[gb + j], ghz = G2[gb + 128 + j], ghn = G2[gb + 256 + j];
    size_t n = (size_t)(row0 + r_);
    float hin = hidden[n * 128 + j];
    float rg = sigmoidf_(gir + ghr);
    float zg = sigmoidf_(giz + ghz);
    float ng = tanhf(gin + rg * ghn);
    outh[n * 128 + j] = (1.f - zg) * ng + zg * hin;
}

extern "C" void kernel_launch(void* const* d_in, const int* in_sizes, int n_in,
                              void* d_out, int out_size, void* d_ws, size_t ws_size,
                              hipStream_t stream)
{
    const float* inputs = (const float*)d_in[0];
    const float* hidden = (const float*)d_in[1];
    const int*   ei     = (const int*)d_in[2];
    const float* ea     = (const float*)d_in[3];
    const float* W1 = (const float*)d_in[4];  const float* b1 = (const float*)d_in[5];
    const float* Wl = (const float*)d_in[6];  const float* bl = (const float*)d_in[7];
    const float* Wr = (const float*)d_in[8];  const float* br = (const float*)d_in[9];
    const float* We = (const float*)d_in[10]; const float* att = (const float*)d_in[11];
    const float* gbias = (const float*)d_in[12];
    const float* Wih = (const float*)d_in[13]; const float* bih = (const float*)d_in[14];
    const float* Whh = (const float*)d_in[15]; const float* bhh = (const float*)d_in[16];
    const float* W2 = (const float*)d_in[17];  const float* b2 = (const float*)d_in[18];

    float* ws = (float*)d_ws;
    float* HCAT  = ws;                                  // N*128
    float* XL    = HCAT + (size_t)NN * 128;             // N*64
    float* XR    = XL + (size_t)NN * 64;                // N*64
    float* AGG   = XR + (size_t)NN * 64;                // N*64
    float* LOOPA = AGG + (size_t)NN * 64;               // N*5
    float* DEG   = LOOPA + (size_t)NN * 5;              // N
    unsigned* MKEY = (unsigned*)(DEG + NN);             // N
    float* DEN   = (float*)(MKEY + NN);                 // N
    float* MM    = DEN + NN;                            // N
    float* LOG   = MM + NN;                             // NE+NN
    float* G     = XL;                                  // reuse xl/xr/agg space after h_gat (needs 2*CHUNK*384 <= 3*N*64)

    float* outq = (float*)d_out;
    float* outh = outq + (size_t)NN * AOUT;

    // zero: AGG, LOOPA, DEG, MKEY, DEN  (contiguous 72*N floats)
    hipMemsetAsync(AGG, 0, (size_t)NN * 72 * sizeof(float), stream);

    deg_kernel<<<NE / 256, 256, 0, stream>>>(ei, ea, DEG, LOOPA);
    loopdiv_kernel<<<NN / 256, 256, 0, stream>>>(DEG, LOOPA);

    // x = relu(inputs @ W1 + b1) -> hcat right half
    gemm_bias_act<<<dim3(NN / 64, 1), 256, 0, stream>>>(inputs, DIN, W1, HH, b1, HCAT + 64, 128, DIN, HH, 1);
    // xl, xr
    gemm_bias_act<<<dim3(NN / 64, 1), 256, 0, stream>>>(HCAT + 64, 128, Wl, HH, bl, XL, HH, HH, HH, 0);
    gemm_bias_act<<<dim3(NN / 64, 1), 256, 0, stream>>>(HCAT + 64, 128, Wr, HH, br, XR, HH, HH, HH, 0);

    edge_logits_kernel<<<8192, 256, 0, stream>>>(ei, ea, LOOPA, XL, XR, We, att, LOG, MKEY);
    decode_kernel<<<NN / 256, 256, 0, stream>>>(MKEY, MM);
    edge_acc_kernel<<<8192, 256, 0, stream>>>(ei, XL, LOG, MM, DEN, AGG);
    hgat_kernel<<<(size_t)NN * 64 / 256, 256, 0, stream>>>(AGG, DEN, gbias, HCAT);

    for (int c = 0; c < NN / CHUNK; ++c) {
        int row0 = c * CHUNK;
        gemm_bias_act<<<dim3(CHUNK / 64, 6), 256, 0, stream>>>(HCAT + (size_t)row0 * 128, 128, Wih, 384, bih, G, 384, 128, 384, 0);
        gemm_bias_act<<<dim3(CHUNK / 64, 6), 256, 0, stream>>>(hidden + (size_t)row0 * 128, 128, Whh, 384, bhh, G + (size_t)CHUNK * 384, 384, 128, 384, 0);
        gru_kernel<<<CHUNK * 128 / 256, 256, 0, stream>>>(G, hidden, outh, row0);
        gemm_bias_act<<<dim3(CHUNK / 64, 1), 256, 0, stream>>>(outh + (size_t)row0 * 128, 128, W2, AOUT, b2, outq + (size_t)row0 * AOUT, AOUT, 128, AOUT, 0);
    }
}

// Round 3
// 2018.548 us; speedup vs baseline: 2.3094x; 2.3094x over previous
//
#include <hip/hip_runtime.h>
#include <cstddef>
#include <cstdint>

#define NN   262144
#define NE   2097152
#define DIN  96
#define HH   64
#define EDD  5
#define AOUT 20
#define CHUNK 32768

__device__ __forceinline__ float sigmoidf_(float x) { return 1.0f / (1.0f + __expf(-x)); }

// ---------------- generic tiled GEMM: C = act(A[M,K] @ W[K,ncols] + bias) ----------------
#define TM 64
#define TN 64
#define KC 32

__global__ __launch_bounds__(256)
void gemm_bias_act(const float* __restrict__ A, int lda,
                   const float* __restrict__ W, int ldw,
                   const float* __restrict__ bias,
                   float* __restrict__ C, int ldc,
                   int K, int ncols, int act)
{
    __shared__ float sA[TM][KC + 1];
    __shared__ float sW[KC][TN];
    const int t = threadIdx.x;
    const int tx = t & 15, ty = t >> 4;
    const int row0 = blockIdx.x * TM;
    const int c0 = blockIdx.y * TN;
    float acc[4][4] = {{0.f}};
    for (int k0 = 0; k0 < K; k0 += KC) {
        for (int i = t; i < TM * KC / 4; i += 256) {
            int r = i >> 3, cq = i & 7;
            float4 v = *(const float4*)(A + (size_t)(row0 + r) * lda + (k0 + cq * 4));
            sA[r][cq * 4 + 0] = v.x; sA[r][cq * 4 + 1] = v.y;
            sA[r][cq * 4 + 2] = v.z; sA[r][cq * 4 + 3] = v.w;
        }
        for (int i = t; i < KC * TN / 4; i += 256) {
            int r = i >> 4, cq = i & 15;
            int c = c0 + cq * 4;
            float4 v = make_float4(0.f, 0.f, 0.f, 0.f);
            if (c < ncols) v = *(const float4*)(W + (size_t)(k0 + r) * ldw + c);
            *(float4*)&sW[r][cq * 4] = v;
        }
        __syncthreads();
#pragma unroll
        for (int k = 0; k < KC; ++k) {
            float a0 = sA[ty * 4 + 0][k], a1 = sA[ty * 4 + 1][k];
            float a2 = sA[ty * 4 + 2][k], a3 = sA[ty * 4 + 3][k];
            float4 w = *(const float4*)&sW[k][tx * 4];
            acc[0][0] += a0 * w.x; acc[0][1] += a0 * w.y; acc[0][2] += a0 * w.z; acc[0][3] += a0 * w.w;
            acc[1][0] += a1 * w.x; acc[1][1] += a1 * w.y; acc[1][2] += a1 * w.z; acc[1][3] += a1 * w.w;
            acc[2][0] += a2 * w.x; acc[2][1] += a2 * w.y; acc[2][2] += a2 * w.z; acc[2][3] += a2 * w.w;
            acc[3][0] += a3 * w.x; acc[3][1] += a3 * w.y; acc[3][2] += a3 * w.z; acc[3][3] += a3 * w.w;
        }
        __syncthreads();
    }
#pragma unroll
    for (int i = 0; i < 4; ++i) {
        size_t rr = (size_t)(row0 + ty * 4 + i);
#pragma unroll
        for (int j = 0; j < 4; ++j) {
            int cc = c0 + tx * 4 + j;
            if (cc < ncols) {
                float v = acc[i][j] + bias[cc];
                if (act) v = fmaxf(v, 0.f);
                C[rr * ldc + cc] = v;
            }
        }
    }
}

// ---------------- CSR build ----------------
__global__ __launch_bounds__(256)
void hist_kernel(const int* __restrict__ ei, int* __restrict__ degi)
{
    int e = blockIdx.x * 256 + threadIdx.x;
    atomicAdd(degi + ei[NE + e], 1);
}

// block scans 1024 nodes (4/thread); slot count per node = deg+1
__global__ __launch_bounds__(256)
void scan1_kernel(const int* __restrict__ degi, int* __restrict__ offl, int* __restrict__ bsum)
{
    __shared__ int s[256];
    const int t = threadIdx.x, b = blockIdx.x;
    const int base = b * 1024 + t * 4;
    int4 d = *(const int4*)(degi + base);
    int c0 = d.x + 1, c1 = d.y + 1, c2 = d.z + 1, c3 = d.w + 1;
    int sum = c0 + c1 + c2 + c3;
    s[t] = sum; __syncthreads();
    for (int ofs = 1; ofs < 256; ofs <<= 1) {
        int v = (t >= ofs) ? s[t - ofs] : 0;
        __syncthreads();
        s[t] += v;
        __syncthreads();
    }
    int excl = s[t] - sum;
    if (t == 255) bsum[b] = s[255];
    offl[base] = excl;
    offl[base + 1] = excl + c0;
    offl[base + 2] = excl + c0 + c1;
    offl[base + 3] = excl + c0 + c1 + c2;
}

__global__ __launch_bounds__(256)
void scan2_kernel(const int* __restrict__ bsum, int* __restrict__ boff)
{
    __shared__ int s[256];
    const int t = threadIdx.x;
    int v0 = bsum[t];
    s[t] = v0; __syncthreads();
    for (int ofs = 1; ofs < 256; ofs <<= 1) {
        int v = (t >= ofs) ? s[t - ofs] : 0;
        __syncthreads();
        s[t] += v;
        __syncthreads();
    }
    boff[t] = s[t] - v0;
}

__global__ __launch_bounds__(256)
void scan3_kernel(const int* __restrict__ offl, const int* __restrict__ boff, int* __restrict__ off)
{
    int i = blockIdx.x * 256 + threadIdx.x;
    off[i] = offl[i] + boff[i >> 10];
    if (i == 0) off[NN] = NE + NN;
}

__global__ __launch_bounds__(256)
void scatter_kernel(const int* __restrict__ ei, const int* __restrict__ off,
                    int* __restrict__ cur, int2* __restrict__ csr)
{
    int e = blockIdx.x * 256 + threadIdx.x;
    int s = ei[e], d = ei[NE + e];
    int pos = atomicAdd(cur + d, 1);
    csr[off[d] + pos] = make_int2(s, e);
}

// ---------------- fused GAT: logits + online softmax + aggregate, no atomics ----------------
__global__ __launch_bounds__(256)
void gat_fused_kernel(const float* __restrict__ xl, const float* __restrict__ xr,
                      const int* __restrict__ off, const int2* __restrict__ csr,
                      const float* __restrict__ ea,
                      const float* __restrict__ We, const float* __restrict__ att,
                      const float* __restrict__ gbias, float* __restrict__ hcat)
{
    __shared__ float sWe[EDD][HH];
    __shared__ float sAtt[HH];
    __shared__ float sGb[HH];
    const int t = threadIdx.x;
    for (int i = t; i < EDD * HH; i += 256) sWe[i / HH][i % HH] = We[i];
    if (t < HH) { sAtt[t] = att[t]; sGb[t] = gbias[t]; }
    __syncthreads();

    const int lane = t & 15;
    const int n = blockIdx.x * 16 + (t >> 4);
    const int c = lane * 4;
    const float at0 = sAtt[c], at1 = sAtt[c + 1], at2 = sAtt[c + 2], at3 = sAtt[c + 3];
    const float4 vr = *(const float4*)(xr + (size_t)n * HH + c);

    const int d0 = off[n], d1 = off[n + 1] - 1;   // real-edge slots
    float m = -1e30f, den = 0.f;
    float4 acc = make_float4(0.f, 0.f, 0.f, 0.f);
    float as0 = 0.f, as1 = 0.f, as2 = 0.f, as3 = 0.f, as4 = 0.f;

    for (int i = d0; i < d1; ++i) {
        int2 se = csr[i];
        const float* pa = ea + (size_t)se.y * EDD;
        float a0 = pa[0], a1 = pa[1], a2 = pa[2], a3 = pa[3], a4 = pa[4];
        as0 += a0; as1 += a1; as2 += a2; as3 += a3; as4 += a4;
        float4 vl = *(const float4*)(xl + (size_t)se.x * HH + c);
        float w0 = a0 * sWe[0][c] + a1 * sWe[1][c] + a2 * sWe[2][c] + a3 * sWe[3][c] + a4 * sWe[4][c];
        float w1 = a0 * sWe[0][c+1] + a1 * sWe[1][c+1] + a2 * sWe[2][c+1] + a3 * sWe[3][c+1] + a4 * sWe[4][c+1];
        float w2 = a0 * sWe[0][c+2] + a1 * sWe[1][c+2] + a2 * sWe[2][c+2] + a3 * sWe[3][c+2] + a4 * sWe[4][c+2];
        float w3 = a0 * sWe[0][c+3] + a1 * sWe[1][c+3] + a2 * sWe[2][c+3] + a3 * sWe[3][c+3] + a4 * sWe[4][c+3];
        float v0 = vl.x + vr.x + w0; v0 = v0 > 0.f ? v0 : 0.2f * v0;
        float v1 = vl.y + vr.y + w1; v1 = v1 > 0.f ? v1 : 0.2f * v1;
        float v2 = vl.z + vr.z + w2; v2 = v2 > 0.f ? v2 : 0.2f * v2;
        float v3 = vl.w + vr.w + w3; v3 = v3 > 0.f ? v3 : 0.2f * v3;
        float part = v0 * at0 + v1 * at1 + v2 * at2 + v3 * at3;
        part += __shfl_xor(part, 1);
        part += __shfl_xor(part, 2);
        part += __shfl_xor(part, 4);
        part += __shfl_xor(part, 8);
        float mn = fmaxf(m, part);
        float sc = __expf(m - mn);
        float p = __expf(part - mn);
        den = den * sc + p;
        acc.x = acc.x * sc + p * vl.x;
        acc.y = acc.y * sc + p * vl.y;
        acc.z = acc.z * sc + p * vl.z;
        acc.w = acc.w * sc + p * vl.w;
        m = mn;
    }

    // self-loop: attr = mean of incoming real-edge attrs
    {
        float degf = (float)(d1 - d0);
        float inv = 1.f / fmaxf(degf, 1.f);
        float a0 = as0 * inv, a1 = as1 * inv, a2 = as2 * inv, a3 = as3 * inv, a4 = as4 * inv;
        float4 vl = *(const float4*)(xl + (size_t)n * HH + c);
        float w0 = a0 * sWe[0][c] + a1 * sWe[1][c] + a2 * sWe[2][c] + a3 * sWe[3][c] + a4 * sWe[4][c];
        float w1 = a0 * sWe[0][c+1] + a1 * sWe[1][c+1] + a2 * sWe[2][c+1] + a3 * sWe[3][c+1] + a4 * sWe[4][c+1];
        float w2 = a0 * sWe[0][c+2] + a1 * sWe[1][c+2] + a2 * sWe[2][c+2] + a3 * sWe[3][c+2] + a4 * sWe[4][c+2];
        float w3 = a0 * sWe[0][c+3] + a1 * sWe[1][c+3] + a2 * sWe[2][c+3] + a3 * sWe[3][c+3] + a4 * sWe[4][c+3];
        float v0 = vl.x + vr.x + w0; v0 = v0 > 0.f ? v0 : 0.2f * v0;
        float v1 = vl.y + vr.y + w1; v1 = v1 > 0.f ? v1 : 0.2f * v1;
        float v2 = vl.z + vr.z + w2; v2 = v2 > 0.f ? v2 : 0.2f * v2;
        float v3 = vl.w + vr.w + w3; v3 = v3 > 0.f ? v3 : 0.2f * v3;
        float part = v0 * at0 + v1 * at1 + v2 * at2 + v3 * at3;
        part += __shfl_xor(part, 1);
        part += __shfl_xor(part, 2);
        part += __shfl_xor(part, 4);
        part += __shfl_xor(part, 8);
        float mn = fmaxf(m, part);
        float sc = __expf(m - mn);
        float p = __expf(part - mn);
        den = den * sc + p;
        acc.x = acc.x * sc + p * vl.x;
        acc.y = acc.y * sc + p * vl.y;
        acc.z = acc.z * sc + p * vl.z;
        acc.w = acc.w * sc + p * vl.w;
    }

    float invden = 1.f / den;
    float4 h;
    h.x = fmaxf(acc.x * invden + sGb[c], 0.f);
    h.y = fmaxf(acc.y * invden + sGb[c + 1], 0.f);
    h.z = fmaxf(acc.z * invden + sGb[c + 2], 0.f);
    h.w = fmaxf(acc.w * invden + sGb[c + 3], 0.f);
    *(float4*)(hcat + (size_t)n * 128 + c) = h;
}

// ---------------- GRU elementwise ----------------
__global__ __launch_bounds__(256)
void gru_kernel(const float* __restrict__ G, const float* __restrict__ hidden,
                float* __restrict__ outh, int row0)
{
    int idx = blockIdx.x * 256 + threadIdx.x;
    int r_ = idx >> 7, j = idx & 127;
    size_t gb = (size_t)r_ * 384;
    const float* G2 = G + (size_t)CHUNK * 384;
    float gir = G[gb + j], giz = G[gb + 128 + j], gin = G[gb + 256 + j];
    float ghr = G2[gb + j], ghz = G2[gb + 128 + j], ghn = G2[gb + 256 + j];
    size_t n = (size_t)(row0 + r_);
    float hin = hidden[n * 128 + j];
    float rg = sigmoidf_(gir + ghr);
    float zg = sigmoidf_(giz + ghz);
    float ng = tanhf(gin + rg * ghn);
    outh[n * 128 + j] = (1.f - zg) * ng + zg * hin;
}

extern "C" void kernel_launch(void* const* d_in, const int* in_sizes, int n_in,
                              void* d_out, int out_size, void* d_ws, size_t ws_size,
                              hipStream_t stream)
{
    const float* inputs = (const float*)d_in[0];
    const float* hidden = (const float*)d_in[1];
    const int*   ei     = (const int*)d_in[2];
    const float* ea     = (const float*)d_in[3];
    const float* W1 = (const float*)d_in[4];  const float* b1 = (const float*)d_in[5];
    const float* Wl = (const float*)d_in[6];  const float* bl = (const float*)d_in[7];
    const float* Wr = (const float*)d_in[8];  const float* br = (const float*)d_in[9];
    const float* We = (const float*)d_in[10]; const float* att = (const float*)d_in[11];
    const float* gbias = (const float*)d_in[12];
    const float* Wih = (const float*)d_in[13]; const float* bih = (const float*)d_in[14];
    const float* Whh = (const float*)d_in[15]; const float* bhh = (const float*)d_in[16];
    const float* W2 = (const float*)d_in[17];  const float* b2 = (const float*)d_in[18];

    float* ws = (float*)d_ws;
    float* HCAT = ws;                                   // N*128
    float* XL   = HCAT + (size_t)NN * 128;              // N*64
    float* XR   = XL + (size_t)NN * 64;                 // N*64
    int*  DEGI  = (int*)(XR + (size_t)NN * 64);         // N
    int*  CUR   = DEGI + NN;                            // N   (contiguous with DEGI for one memset)
    int*  OFFL  = CUR + NN;                             // N
    int*  OFF   = OFFL + NN;                            // N+1
    int*  BSUM  = OFF + NN + 1;                         // 256
    int*  BOFF  = BSUM + 256;                           // 256
    int2* CSR   = (int2*)(((uintptr_t)(BOFF + 256) + 15) & ~(uintptr_t)15);  // NE int2
    float* G    = XL;                                   // GRU scratch reuse (2*CHUNK*384 <= 2*N*64)

    float* outq = (float*)d_out;
    float* outh = outq + (size_t)NN * AOUT;

    // zero DEGI + CUR
    hipMemsetAsync(DEGI, 0, (size_t)2 * NN * sizeof(int), stream);

    // CSR build
    hist_kernel<<<NE / 256, 256, 0, stream>>>(ei, DEGI);
    scan1_kernel<<<NN / 1024, 256, 0, stream>>>(DEGI, OFFL, BSUM);
    scan2_kernel<<<1, 256, 0, stream>>>(BSUM, BOFF);
    scan3_kernel<<<NN / 256, 256, 0, stream>>>(OFFL, BOFF, OFF);
    scatter_kernel<<<NE / 256, 256, 0, stream>>>(ei, OFF, CUR, CSR);

    // x = relu(inputs @ W1 + b1) -> hcat right half
    gemm_bias_act<<<dim3(NN / 64, 1), 256, 0, stream>>>(inputs, DIN, W1, HH, b1, HCAT + 64, 128, DIN, HH, 1);
    // xl, xr
    gemm_bias_act<<<dim3(NN / 64, 1), 256, 0, stream>>>(HCAT + 64, 128, Wl, HH, bl, XL, HH, HH, HH, 0);
    gemm_bias_act<<<dim3(NN / 64, 1), 256, 0, stream>>>(HCAT + 64, 128, Wr, HH, br, XR, HH, HH, HH, 0);

    // fused GAT -> hcat left half
    gat_fused_kernel<<<NN / 16, 256, 0, stream>>>(XL, XR, OFF, CSR, ea, We, att, gbias, HCAT);

    for (int c = 0; c < NN / CHUNK; ++c) {
        int row0 = c * CHUNK;
        gemm_bias_act<<<dim3(CHUNK / 64, 6), 256, 0, stream>>>(HCAT + (size_t)row0 * 128, 128, Wih, 384, bih, G, 384, 128, 384, 0);
        gemm_bias_act<<<dim3(CHUNK / 64, 6), 256, 0, stream>>>(hidden + (size_t)row0 * 128, 128, Whh, 384, bhh, G + (size_t)CHUNK * 384, 384, 128, 384, 0);
        gru_kernel<<<CHUNK * 128 / 256, 256, 0, stream>>>(G, hidden, outh, row0);
        gemm_bias_act<<<dim3(CHUNK / 64, 1), 256, 0, stream>>>(outh + (size_t)row0 * 128, 128, W2, AOUT, b2, outq + (size_t)row0 * AOUT, AOUT, 128, AOUT, 0);
    }
}